// Round 1
// baseline (502.900 us; speedup 1.0000x reference)
//
#include <hip/hip_runtime.h>

#define DIM 4096
#define TOTAL 16384
#define WIDTH 4
#define STATE_LEN 3
#define BATCH 8
#define NSLOTS 256
#define TVEC (TOTAL / 4)   // 4096 float4 per row

// out[d,t] = w[d,0]*x[t-3] + w[d,1]*x[t-2] + w[d,2]*x[t-1] + w[d,3]*x[t]  (+ x[t] residual)
// with x[t-dd] replaced per varlen/init-state rules when p = t - seg_start < dd.
__global__ __launch_bounds__(256) void conv_out_kernel(
    const float* __restrict__ x, const float* __restrict__ weight,
    const float* __restrict__ cs, const int* __restrict__ qsl,
    const int* __restrict__ cache_indices, const int* __restrict__ init_mode,
    const int* __restrict__ pad_p, const int* __restrict__ res_p,
    float* __restrict__ out)
{
    __shared__ int s_qsl[BATCH + 1];
    __shared__ int s_ci[BATCH];
    __shared__ int s_im[BATCH];
    __shared__ int s_pad, s_res;
    if (threadIdx.x < BATCH + 1) s_qsl[threadIdx.x] = qsl[threadIdx.x];
    if (threadIdx.x >= 32 && threadIdx.x < 32 + BATCH) s_ci[threadIdx.x - 32] = cache_indices[threadIdx.x - 32];
    if (threadIdx.x >= 64 && threadIdx.x < 64 + BATCH) s_im[threadIdx.x - 64] = init_mode[threadIdx.x - 64];
    if (threadIdx.x == 96) s_pad = pad_p[0];
    if (threadIdx.x == 97) s_res = res_p[0];
    __syncthreads();

    unsigned v = blockIdx.x * 256u + threadIdx.x;   // global float4 index
    int d  = v >> 12;          // v / TVEC
    int tv = v & (TVEC - 1);
    int t0 = tv << 2;

    const float4* xr = (const float4*)(x + (size_t)d * TOTAL);
    float4 cur = xr[tv];
    float4 prev = make_float4(0.f, 0.f, 0.f, 0.f);
    if (tv > 0) prev = xr[tv - 1];
    // win[3+i] = x[t0+i]; x[t-dd] = win[3+i-dd]
    float win[7] = {prev.y, prev.z, prev.w, cur.x, cur.y, cur.z, cur.w};

    float4 w = ((const float4*)weight)[d];   // uniform within block

    // segment for t0 (qsl[seg] <= t < qsl[seg+1], empty segs skipped like searchsorted-right)
    int seg = 0;
    while (seg + 1 < BATCH && t0 >= s_qsl[seg + 1]) seg++;

    float res[4];
    #pragma unroll
    for (int i = 0; i < 4; i++) {
        int t = t0 + i;
        while (seg + 1 < BATCH && t >= s_qsl[seg + 1]) seg++;
        int p = t - s_qsl[seg];
        float xt = win[3 + i];
        float acc;
        if (p >= 3) {
            // fast path: everything from x
            acc = w.x * win[i] + w.y * win[i + 1] + w.z * win[i + 2] + w.w * xt;
        } else {
            int raw = s_ci[seg];
            bool valid = (raw != s_pad);
            int slot = valid ? raw : 0;
            bool use_init = valid && (s_im[seg] != 0);
            const float* csrow = cs + ((size_t)slot * DIM + d) * STATE_LEN;
            // st_idx = STATE_LEN - dd + p  (in range, no clip needed for p < dd)
            float xm1 = (p >= 1) ? win[i + 2] : (use_init ? csrow[2 + p] : 0.f);
            float xm2 = (p >= 2) ? win[i + 1] : (use_init ? csrow[1 + p] : 0.f);
            float xm3 =                          (use_init ? csrow[0 + p] : 0.f);
            acc = w.x * xm3 + w.y * xm2 + w.z * xm1 + w.w * xt;
        }
        if (s_res) acc += xt;
        res[i] = acc;
    }
    ((float4*)(out + (size_t)d * TOTAL))[tv] = make_float4(res[0], res[1], res[2], res[3]);
}

// Overwrite the BATCH touched slots in the copied-out conv_states.
__global__ __launch_bounds__(256) void state_update_kernel(
    const float* __restrict__ x, const float* __restrict__ cs,
    const int* __restrict__ qsl, const int* __restrict__ cache_indices,
    const int* __restrict__ init_mode, const int* __restrict__ pad_p,
    float* __restrict__ out_states)
{
    int idx = blockIdx.x * blockDim.x + threadIdx.x;   // b * DIM + d
    if (idx >= BATCH * DIM) return;
    int b = idx >> 12;            // / DIM
    int d = idx & (DIM - 1);
    int pad = pad_p[0];
    int raw = cache_indices[b];
    if (raw == pad) return;       // dropped scatter
    int start = qsl[b], end = qsl[b + 1];
    int L = end - start;
    bool init = (init_mode[b] != 0);
    const float* xrow  = x + (size_t)d * TOTAL;
    const float* csrow = cs + ((size_t)raw * DIM + d) * STATE_LEN;
    float*       orow  = out_states + ((size_t)raw * DIM + d) * STATE_LEN;
    #pragma unroll
    for (int j = 0; j < STATE_LEN; j++) {
        int gx = end + j - STATE_LEN;
        float val;
        if (gx >= start) {
            val = xrow[gx];
        } else if (init) {
            int sidx = L + j;
            if (sidx < 0) sidx = 0;
            if (sidx > STATE_LEN - 1) sidx = STATE_LEN - 1;
            val = csrow[sidx];
        } else {
            val = 0.f;
        }
        orow[j] = val;
    }
}

extern "C" void kernel_launch(void* const* d_in, const int* in_sizes, int n_in,
                              void* d_out, int out_size, void* d_ws, size_t ws_size,
                              hipStream_t stream) {
    const float* x      = (const float*)d_in[0];
    const float* weight = (const float*)d_in[1];
    const float* cs     = (const float*)d_in[2];
    const int*   qsl    = (const int*)d_in[3];
    const int*   ci     = (const int*)d_in[4];
    const int*   im     = (const int*)d_in[5];
    const int*   pad    = (const int*)d_in[6];
    const int*   res    = (const int*)d_in[7];

    float* out        = (float*)d_out;
    float* out_states = out + (size_t)DIM * TOTAL;

    // Output 1 baseline: copy of conv_states (d_out is re-poisoned every call)
    hipMemcpyAsync(out_states, cs, (size_t)NSLOTS * DIM * STATE_LEN * sizeof(float),
                   hipMemcpyDeviceToDevice, stream);

    // Output 0: conv result
    conv_out_kernel<<<(DIM * TVEC) / 256, 256, 0, stream>>>(
        x, weight, cs, qsl, ci, im, pad, res, out);

    // Output 1: overwrite updated slots
    state_update_kernel<<<(BATCH * DIM + 255) / 256, 256, 0, stream>>>(
        x, cs, qsl, ci, im, pad, out_states);
}